// Round 1
// baseline (75.239 us; speedup 1.0000x reference)
//
#include <hip/hip_runtime.h>

// images: (64, 3, 512, 512) float32, NCHW. Plane = 512*512 = 262144 floats.
// Per pixel: rgb->hsv, s = clamp(s*2, 0, 1), hsv->rgb.
// Memory-bound: float4 per thread per plane (4 pixels/thread).

#define PLANE 262144            // 512*512
#define GROUPS_PER_IMG (PLANE / 4)   // 65536 float4-groups per plane

__device__ __forceinline__ void saturate_px(float r, float g, float b,
                                            float& ro, float& go, float& bo) {
    float maxc = fmaxf(fmaxf(r, g), b);
    float minc = fminf(fminf(r, g), b);
    float delta = maxc - minc;
    float delta_s = (delta > 0.0f) ? delta : 1.0f;

    // hue, matching jnp.where chain (maxc==r branch wins ties, then maxc==g)
    float h = (maxc == r) ? (g - b) / delta_s
            : (maxc == g) ? 2.0f + (b - r) / delta_s
                          : 4.0f + (r - g) / delta_s;
    float h6 = h * (1.0f / 6.0f);
    h = (delta > 0.0f) ? (h6 - floorf(h6)) : 0.0f;   // python %1.0 -> [0,1)

    float s = (maxc > 0.0f) ? delta / maxc : 0.0f;
    s = fminf(fmaxf(s * 2.0f, 0.0f), 1.0f);          // SAT_MUL=2, SAT_ADD=0

    // hsv -> rgb: f(n) = v - v*s*clip(min(k, 4-k), 0, 1), k = (n + 6h) % 6
    float vs = maxc * s;
    float h6x = h * 6.0f;                            // in [0, 6)

    float k;
    k = 5.0f + h6x; if (k >= 6.0f) k -= 6.0f;        // n + 6h in [5,11)
    ro = maxc - vs * fmaxf(fminf(fminf(k, 4.0f - k), 1.0f), 0.0f);
    k = 3.0f + h6x; if (k >= 6.0f) k -= 6.0f;        // [3,9)
    go = maxc - vs * fmaxf(fminf(fminf(k, 4.0f - k), 1.0f), 0.0f);
    k = 1.0f + h6x; if (k >= 6.0f) k -= 6.0f;        // [1,7)
    bo = maxc - vs * fmaxf(fminf(fminf(k, 4.0f - k), 1.0f), 0.0f);
}

__global__ __launch_bounds__(256) void Saturate_32040456028507_kernel(
        const float* __restrict__ in, float* __restrict__ out, int ngroups) {
    int t = blockIdx.x * blockDim.x + threadIdx.x;
    if (t >= ngroups) return;

    int img = t >> 16;                  // t / GROUPS_PER_IMG
    int j   = t & (GROUPS_PER_IMG - 1); // within-plane float4 index
    long base = (long)img * (3L * PLANE) + (long)j * 4;

    float4 rv = *reinterpret_cast<const float4*>(in + base);
    float4 gv = *reinterpret_cast<const float4*>(in + base + PLANE);
    float4 bv = *reinterpret_cast<const float4*>(in + base + 2 * PLANE);

    float4 ro, go, bo;
    saturate_px(rv.x, gv.x, bv.x, ro.x, go.x, bo.x);
    saturate_px(rv.y, gv.y, bv.y, ro.y, go.y, bo.y);
    saturate_px(rv.z, gv.z, bv.z, ro.z, go.z, bo.z);
    saturate_px(rv.w, gv.w, bv.w, ro.w, go.w, bo.w);

    *reinterpret_cast<float4*>(out + base)             = ro;
    *reinterpret_cast<float4*>(out + base + PLANE)     = go;
    *reinterpret_cast<float4*>(out + base + 2 * PLANE) = bo;
}

extern "C" void kernel_launch(void* const* d_in, const int* in_sizes, int n_in,
                              void* d_out, int out_size, void* d_ws, size_t ws_size,
                              hipStream_t stream) {
    const float* in = (const float*)d_in[0];
    float* out = (float*)d_out;

    int total = in_sizes[0];            // 64*3*512*512
    int ngroups = total / 12;           // 4 pixels per thread, 3 channels

    int block = 256;
    int grid = (ngroups + block - 1) / block;
    Saturate_32040456028507_kernel<<<grid, block, 0, stream>>>(in, out, ngroups);
}

// Round 3
// 63.349 us; speedup vs baseline: 1.1877x; 1.1877x over previous
//
#include <hip/hip_runtime.h>

// images: (64, 3, 512, 512) float32, NCHW. Plane = 512*512 = 262144 floats.
// Per pixel: rgb->hsv, s = clamp(s*2, 0, 1), hsv->rgb.
// Memory-bound. float4 per thread per plane (4 pixels/thread).
// R1/R2: NON-TEMPORAL stores. Input (201 MB) fits Infinity Cache (256 MB);
// regular stores evict it between graph replays. nt stores keep input
// L3-resident -> steady-state HBM traffic ~= writes only.
// R2 fix: vector elements can't bind to float& -- compute in scalars,
// assemble the vector afterwards.

#define PLANE 262144                 // 512*512
#define GROUPS_PER_IMG (PLANE / 4)   // 65536 float4-groups per plane

typedef float v4f __attribute__((ext_vector_type(4)));

__device__ __forceinline__ void saturate_px(float r, float g, float b,
                                            float& ro, float& go, float& bo) {
    float maxc = fmaxf(fmaxf(r, g), b);
    float minc = fminf(fminf(r, g), b);
    float delta = maxc - minc;
    float delta_s = (delta > 0.0f) ? delta : 1.0f;

    // hue, matching jnp.where chain (maxc==r branch wins ties, then maxc==g)
    float h = (maxc == r) ? (g - b) / delta_s
            : (maxc == g) ? 2.0f + (b - r) / delta_s
                          : 4.0f + (r - g) / delta_s;
    float h6 = h * (1.0f / 6.0f);
    h = (delta > 0.0f) ? (h6 - floorf(h6)) : 0.0f;   // python %1.0 -> [0,1)

    float s = (maxc > 0.0f) ? delta / maxc : 0.0f;
    s = fminf(fmaxf(s * 2.0f, 0.0f), 1.0f);          // SAT_MUL=2, SAT_ADD=0

    // hsv -> rgb: f(n) = v - v*s*clip(min(k, 4-k), 0, 1), k = (n + 6h) % 6
    float vs = maxc * s;
    float h6x = h * 6.0f;                            // in [0, 6)

    float k;
    k = 5.0f + h6x; if (k >= 6.0f) k -= 6.0f;        // n + 6h in [5,11)
    ro = maxc - vs * fmaxf(fminf(fminf(k, 4.0f - k), 1.0f), 0.0f);
    k = 3.0f + h6x; if (k >= 6.0f) k -= 6.0f;        // [3,9)
    go = maxc - vs * fmaxf(fminf(fminf(k, 4.0f - k), 1.0f), 0.0f);
    k = 1.0f + h6x; if (k >= 6.0f) k -= 6.0f;        // [1,7)
    bo = maxc - vs * fmaxf(fminf(fminf(k, 4.0f - k), 1.0f), 0.0f);
}

__global__ __launch_bounds__(256) void Saturate_32040456028507_kernel(
        const float* __restrict__ in, float* __restrict__ out, int ngroups) {
    int t = blockIdx.x * blockDim.x + threadIdx.x;
    if (t >= ngroups) return;

    int img = t >> 16;                  // t / GROUPS_PER_IMG
    int j   = t & (GROUPS_PER_IMG - 1); // within-plane float4 index
    long base = (long)img * (3L * PLANE) + (long)j * 4;

    v4f rv = *reinterpret_cast<const v4f*>(in + base);
    v4f gv = *reinterpret_cast<const v4f*>(in + base + PLANE);
    v4f bv = *reinterpret_cast<const v4f*>(in + base + 2 * PLANE);

    float r0, g0, b0, r1, g1, b1, r2, g2, b2, r3, g3, b3;
    saturate_px(rv.x, gv.x, bv.x, r0, g0, b0);
    saturate_px(rv.y, gv.y, bv.y, r1, g1, b1);
    saturate_px(rv.z, gv.z, bv.z, r2, g2, b2);
    saturate_px(rv.w, gv.w, bv.w, r3, g3, b3);

    v4f ro = {r0, r1, r2, r3};
    v4f go = {g0, g1, g2, g3};
    v4f bo = {b0, b1, b2, b3};

    __builtin_nontemporal_store(ro, reinterpret_cast<v4f*>(out + base));
    __builtin_nontemporal_store(go, reinterpret_cast<v4f*>(out + base + PLANE));
    __builtin_nontemporal_store(bo, reinterpret_cast<v4f*>(out + base + 2 * PLANE));
}

extern "C" void kernel_launch(void* const* d_in, const int* in_sizes, int n_in,
                              void* d_out, int out_size, void* d_ws, size_t ws_size,
                              hipStream_t stream) {
    const float* in = (const float*)d_in[0];
    float* out = (float*)d_out;

    int total = in_sizes[0];            // 64*3*512*512
    int ngroups = total / 12;           // 4 pixels per thread, 3 channels

    int block = 256;
    int grid = (ngroups + block - 1) / block;
    Saturate_32040456028507_kernel<<<grid, block, 0, stream>>>(in, out, ngroups);
}